// Round 3
// baseline (455.374 us; speedup 1.0000x reference)
//
#include <hip/hip_runtime.h>
#include <hip/hip_bf16.h>
#include <cstdint>
#include <cstddef>

#define N_ACT 200000
#define CH 128
#define NOFF 27
#define TM 128

typedef __bf16 v8bf __attribute__((ext_vector_type(8)));
typedef float v4f __attribute__((ext_vector_type(4)));

__device__ __forceinline__ unsigned short f2bf(float f) {
    union { float f; unsigned int u; } x; x.f = f;
    unsigned int lsb = (x.u >> 16) & 1u;
    x.u += 0x7fffu + lsb;            // round-to-nearest-even
    return (unsigned short)(x.u >> 16);
}

// K1a: cast features fp32 -> bf16, 8 elements/thread
__global__ void cast_feat(const float* __restrict__ in,
                          unsigned short* __restrict__ out) {
    long long i = (long long)blockIdx.x * blockDim.x + threadIdx.x;
    long long base = i * 8;
    if (base >= (long long)N_ACT * CH) return;
    const float4* p = (const float4*)(in + base);
    float4 a = p[0], b = p[1];
    unsigned int w0 = (unsigned)f2bf(a.x) | ((unsigned)f2bf(a.y) << 16);
    unsigned int w1 = (unsigned)f2bf(a.z) | ((unsigned)f2bf(a.w) << 16);
    unsigned int w2 = (unsigned)f2bf(b.x) | ((unsigned)f2bf(b.y) << 16);
    unsigned int w3 = (unsigned)f2bf(b.z) | ((unsigned)f2bf(b.w) << 16);
    *(uint4*)(out + base) = make_uint4(w0, w1, w2, w3);
}

// K1b: pack W[k][cin][cout] fp32 into fragment-order bf16:
//   Wtp[(k*4+q)*4096 + (jkk*64 + lane)*8 + e]
// q = col-quarter, jkk = j*4+kk, lane = quad*16+lr,
// value = W[k][kk*32+quad*8+e][q*32+j*16+lr].
// -> a wave's b-frag loads are 64 lanes x consecutive 16B (1 KB) each.
__global__ void prep_w(const float* __restrict__ W,
                       unsigned short* __restrict__ Wtp,
                       float* __restrict__ stats,
                       float* __restrict__ zpage) {
    int k = blockIdx.x;
    int t = threadIdx.x;
    if (k == 0 && t < 2 * CH) stats[t] = 0.0f;   // sums + sumsq
    if (k == 0 && t < 64) zpage[t] = 0.0f;       // 256 B zero row for gathers
    const float* wk = W + (size_t)k * CH * CH;
    for (int g = t; g < 2048; g += 256) {
        int q = g >> 9, r = g & 511;
        int jkk = r >> 6, lane = r & 63;
        int j = jkk >> 2, kk = jkk & 3;
        int lr = lane & 15, quad = lane >> 4;
        int cout = q * 32 + j * 16 + lr;
        int cin0 = kk * 32 + quad * 8;
        unsigned int wbuf[4];
        #pragma unroll
        for (int h = 0; h < 4; ++h) {
            unsigned short lo = f2bf(wk[(size_t)(cin0 + 2*h)     * CH + cout]);
            unsigned short hi = f2bf(wk[(size_t)(cin0 + 2*h + 1) * CH + cout]);
            wbuf[h] = (unsigned)lo | ((unsigned)hi << 16);
        }
        *(uint4*)(Wtp + ((size_t)(k * 4 + q) << 12) + (size_t)(jkk * 64 + lane) * 8)
            = make_uint4(wbuf[0], wbuf[1], wbuf[2], wbuf[3]);
    }
}

// K2: single-LDS-buffer, 2-barrier pipeline; 2x2 wave grid of 64x64 tiles.
// Each wave computes 64 rows x 64 couts -> reads only HALF the A-tile from
// LDS per k (16 b128/lane vs 32), cutting per-block-k LDS traffic from
// 160 KB to 96 KB (the CU-shared LDS pipe was the contended resource).
// B doubles to 16 frags (64 VGPR) sourced from the L2-resident Wtp.
__global__ __launch_bounds__(256, 2) void conv_mfma(
        const unsigned short* __restrict__ feat,   // [N][128] bf16
        const int* __restrict__ nbr,               // [27][N]
        const unsigned short* __restrict__ Wtp,    // packed (see prep_w)
        const unsigned short* __restrict__ zpage,  // 256 B of zeros
        float* __restrict__ out,                   // [N][128] conv result
        float* __restrict__ stats) {               // sums[128], sumsq[128]
    __shared__ __bf16 As[TM * CH];                 // 32 KB, rotated chunks
    __shared__ int idxL[NOFF * TM];                // 13.8 KB
    __shared__ float sred[512];                    // 2 KB

    const int t    = threadIdx.x;
    const int row0 = blockIdx.x * TM;
    const int wid  = t >> 6;
    const int lane = t & 63;
    const int lr   = lane & 15;
    const int quad = lane >> 4;
    const int wr   = wid >> 1;      // row-half of this wave   (0..1)
    const int wc   = wid & 1;       // cout-half of this wave  (0..1)

    // ---- stage the whole neighbor-index table once (coalesced)
    for (int e = t; e < NOFF * TM; e += 256) {
        int k = e >> 7, r = e & 127;
        int gr = row0 + r;
        idxL[e] = (gr < N_ACT) ? nbr[(size_t)k * N_ACT + gr] : -1;
    }
    __syncthreads();

    v4f acc[4][4];
    #pragma unroll
    for (int i = 0; i < 4; ++i)
        #pragma unroll
        for (int j = 0; j < 4; ++j)
            acc[i][j] = (v4f){0.f, 0.f, 0.f, 0.f};

    // staging coords: thread t gathers chunk sc (16B) of rows p*16+sr0
    const int sc  = t & 15;
    const int sr0 = t >> 4;
    const unsigned short* zsrc = zpage + sc * 8;

    v8bf B[16];          // B[j*4+kk]: 64 couts x 128 cin for this wave

    // gather + immediate LDS write: G regs live only inside this function
    auto stageA = [&](int k) {
        uint4 G[8];
        #pragma unroll
        for (int p = 0; p < 8; ++p) {
            int row = p * 16 + sr0;
            int idx = idxL[k * TM + row];
            const unsigned short* src =
                (idx >= 0) ? feat + ((size_t)idx << 7) + sc * 8 : zsrc;
            G[p] = *(const uint4*)src;
        }
        #pragma unroll
        for (int p = 0; p < 8; ++p) {
            int row = p * 16 + sr0;
            *(uint4*)(As + row * CH + (((sc + row) & 15) << 3)) = G[p];
        }
    };
    // wave wc needs cout quarters {2wc, 2wc+1}; prep_w layout unchanged
    auto loadB = [&](int k) {
        #pragma unroll
        for (int j = 0; j < 4; ++j) {
            const unsigned short* base = Wtp
                + ((size_t)(k * 4 + 2 * wc + (j >> 1)) << 12)
                + (size_t)(((j & 1) * 4) * 64 + lane) * 8;
            #pragma unroll
            for (int kk = 0; kk < 4; ++kk)
                B[j * 4 + kk] = *(const v8bf*)(base + kk * 512);
        }
    };
    // per 16-row subtile: load 4 a-frags (16 regs), fire 16 MFMAs (4x reuse)
    auto mfmaPhase = [&]() {
        #pragma unroll
        for (int i = 0; i < 4; ++i) {
            const __bf16* rowp = As + (wr * 64 + i * 16 + lr) * CH;
            v8bf a[4];
            #pragma unroll
            for (int kk = 0; kk < 4; ++kk)
                a[kk] = *(const v8bf*)(rowp + (((kk * 4 + quad + lr) & 15) << 3));
            #pragma unroll
            for (int kk = 0; kk < 4; ++kk) {
                #pragma unroll
                for (int j = 0; j < 4; ++j)
                    acc[i][j] = __builtin_amdgcn_mfma_f32_16x16x32_bf16(
                        a[kk], B[j * 4 + kk], acc[i][j], 0, 0, 0);
            }
        }
    };

    // ---- prologue: stage k=0
    stageA(0);
    loadB(0);
    __syncthreads();

    // ---- k-loop: 2 barriers, single buffer, no G-hold across MFMA
    #pragma unroll 1
    for (int k = 0; k < NOFF; ++k) {
        mfmaPhase();
        if (k + 1 < NOFF) {
            __syncthreads();       // everyone done reading As / B consumed
            stageA(k + 1);         // gather -> immediate ds_write (G dies)
            loadB(k + 1);          // B latency hides behind gather drain
            __syncthreads();       // stage complete
        }
    }

    // ---- epilogue: store conv result (nontemporal: written once, read once
    // much later by bn_relu; keep it from evicting feat from L3) + stats
    float psum[4] = {0.f, 0.f, 0.f, 0.f};
    float psq[4]  = {0.f, 0.f, 0.f, 0.f};
    #pragma unroll
    for (int i = 0; i < 4; ++i) {
        #pragma unroll
        for (int r = 0; r < 4; ++r) {
            int grow = row0 + wr * 64 + i * 16 + quad * 4 + r;
            if (grow < N_ACT) {
                #pragma unroll
                for (int j = 0; j < 4; ++j) {
                    float v = acc[i][j][r];
                    __builtin_nontemporal_store(
                        v, &out[(size_t)grow * CH + wc * 64 + j * 16 + lr]);
                    psum[j] += v;
                    psq[j]  += v * v;
                }
            }
        }
    }
    #pragma unroll
    for (int j = 0; j < 4; ++j) {
        psum[j] += __shfl_xor(psum[j], 16, 64);
        psq[j]  += __shfl_xor(psq[j], 16, 64);
        psum[j] += __shfl_xor(psum[j], 32, 64);
        psq[j]  += __shfl_xor(psq[j], 32, 64);
    }
    if (quad == 0) {
        #pragma unroll
        for (int j = 0; j < 4; ++j) {
            int c = wc * 64 + j * 16 + lr;
            sred[wr * CH + c]           = psum[j];
            sred[2 * CH + wr * CH + c]  = psq[j];
        }
    }
    __syncthreads();
    if (t < CH) {
        atomicAdd(&stats[t],      sred[t] + sred[CH + t]);
        atomicAdd(&stats[CH + t], sred[2 * CH + t] + sred[3 * CH + t]);
    }
}

// K3: per-channel scale/shift from batch stats
__global__ void finalize_stats(const float* __restrict__ gamma,
                               const float* __restrict__ beta,
                               float* __restrict__ stats) {
    int c = threadIdx.x;
    if (c < CH) {
        float inv_n = 1.0f / (float)N_ACT;
        float mean  = stats[c] * inv_n;
        float var   = stats[CH + c] * inv_n - mean * mean;
        float sc    = gamma[c] * rsqrtf(var + 1e-4f);
        stats[2 * CH + c] = sc;
        stats[3 * CH + c] = beta[c] - mean * sc;
    }
}

// K4: out = relu(conv * scale[c] + shift[c]), ext-vector float4 nt streaming
__global__ void bn_relu(const float* __restrict__ conv,
                        const float* __restrict__ stats,
                        float* __restrict__ out) {
    long long i = (long long)blockIdx.x * blockDim.x + threadIdx.x;
    if (i >= (long long)N_ACT * CH / 4) return;
    int c4 = (int)(i & 31) * 4;
    v4f v  = __builtin_nontemporal_load((const v4f*)conv + i);
    v4f sc = *(const v4f*)(stats + 2 * CH + c4);
    v4f sh = *(const v4f*)(stats + 3 * CH + c4);
    v4f o;
    o[0] = fmaxf(v[0] * sc[0] + sh[0], 0.f);
    o[1] = fmaxf(v[1] * sc[1] + sh[1], 0.f);
    o[2] = fmaxf(v[2] * sc[2] + sh[2], 0.f);
    o[3] = fmaxf(v[3] * sc[3] + sh[3], 0.f);
    __builtin_nontemporal_store(o, (v4f*)out + i);
}

extern "C" void kernel_launch(void* const* d_in, const int* in_sizes, int n_in,
                              void* d_out, int out_size, void* d_ws, size_t ws_size,
                              hipStream_t stream) {
    const float* features = (const float*)d_in[0];
    const int*   nbr      = (const int*)d_in[1];
    const float* W        = (const float*)d_in[2];
    const float* gamma    = (const float*)d_in[3];
    const float* beta     = (const float*)d_in[4];
    float* outp = (float*)d_out;

    char* ws = (char*)d_ws;
    // layout: feat_bf16 (51,200,000 B) | Wtp (884,736 B) | conv fp32
    // (102,400,000 B) | stats (512 floats) | zero page (256 B)
    unsigned short* feat_bf = (unsigned short*)ws;
    unsigned short* Wtp     = (unsigned short*)(ws + 51200000);
    float* conv             = (float*)(ws + 51200000 + 884736);
    float* stats            = (float*)(ws + 51200000 + 884736 + 102400000);
    float* zpage            = stats + 4 * CH;

    cast_feat<<<12500, 256, 0, stream>>>(features, feat_bf);
    prep_w<<<NOFF, 256, 0, stream>>>(W, Wtp, stats, zpage);
    conv_mfma<<<(N_ACT + TM - 1) / TM, 256, 0, stream>>>(
        feat_bf, nbr, Wtp, (const unsigned short*)zpage, conv, stats);
    finalize_stats<<<1, CH, 0, stream>>>(gamma, beta, stats);
    bn_relu<<<25000, 256, 0, stream>>>(conv, stats, outp);
}